// Round 8
// baseline (9.798 us; speedup 1.0000x reference)
//
#include <hip/hip_runtime.h>
#include <stdint.h>

// KANRNNEncoder: T=1024 scan has dependency horizon 2 (only h[:, :24] feeds
// the recurrence; those columns are pure functions of x at the previous
// step). Entire scan collapses to a closed form over x[:, T-2:T, :].
//
// R1: W_lat staged in LDS, lane-rotated dot.                  14.2 -> 10.4 us
// R2: K-split via MORE BLOCKS: REGRESSED (18.9) — per-block fixed cost rules.
// R3: 512 thr (2 waves/SIMD), wave-pair K-split, gload_lds W.  -> 9.6 us
// R4: padded-W + uniform-hv: REGRESSED (11.4).
// R5: 1024 thr (4 waves/SIMD): REGRESSED (10.8).
// R6: hT in VGPRs + readlane, W LDS-read once (64KB): NULL (9.8). LDS
//     traffic is not the binding term — the block's serial skeleton is.
// R7: delete the skeleton: NO W staging, NO first barrier. W read directly
//     from global in the dot — in this partition lane l's 8 chunks are ONE
//     128B line (line-perfect, L1-cached after the first b128), so traffic
//     is identical to staging (64KB/block) without the vmcnt(0)+barrier
//     drain. LDS shrinks to the 8KB partial buffer + 1 barrier. Sigmoid
//     divide -> v_rcp_f32 (+1ULP, threshold 3e-2).

constexpr int Bc = 1024, Tc = 1024, Fc = 8, Hc = 256, Kc = 8, Lc = 64;

__device__ __forceinline__ float sigm(float v) {
    return __builtin_amdgcn_rcpf(1.0f + __expf(-v));
}
__device__ __forceinline__ float rdlane(float v, int lane) {
    return __uint_as_float(__builtin_amdgcn_readlane(__float_as_uint(v), lane));
}

__global__ __launch_bounds__(512) void kan_rnn_collapsed(
    const float* __restrict__ x,     // (B,T,F)
    const float* __restrict__ a_in,  // (F,K) flat 64
    const float* __restrict__ b_in,  // (F,K)
    const float* __restrict__ a_h,   // (H,K) flat 2048
    const float* __restrict__ b_h,   // (H,K)
    const float* __restrict__ W,     // (L,H) 64x256
    const float* __restrict__ bl,    // (L,)
    float* __restrict__ out)         // (B,L)
{
    __shared__ float part[8][4][Lc];  // 8 KB: [wave][row][col]
    const int t  = threadIdx.x;
    const int w  = t >> 6;            // wave 0..7
    const int l  = t & 63;            // lane

    // ---- hT word for this wave (all 4 rows), lane-distributed in VGPRs ----
    // Wave w consumes h-indices [32w, 32w+32) -> hT word widx = w>>1.
    // hh[r] at lane λ holds hT_r[64*widx + λ].
    const int widx = w >> 1;
    const float* xb = x + (size_t)(blockIdx.x * 4) * Tc * Fc;   // block's row 0
    float hh[4];
    if (widx == 0) {          // input-basis entries: c = lane
        #pragma unroll
        for (int r = 0; r < 4; ++r) {
            const float x1 = xb[r * Tc * Fc + (Tc - 1) * Fc + (l >> 3)];
            hh[r] = sigm(2.0f * sigm(a_in[l] * (x1 - b_in[l])));
        }
    } else {                  // hidden-basis entries: c = 64 + 64m + lane, m = widx-1
        const int m = widx - 1, hp = (l >> 3) + 8 * m, j = l + 64 * m;
        const float ai = a_in[hp], bi = b_in[hp], ah = a_h[j], bh = b_h[j];
        #pragma unroll
        for (int r = 0; r < 4; ++r) {
            const float x2 = xb[r * Tc * Fc + (Tc - 2) * Fc + m];
            const float s  = sigm(2.0f * sigm(ai * (x2 - bi)));
            hh[r] = sigm(2.0f * sigm(ah * (s - bh)));
        }
    }

    // ---- dot: wave w covers chunks q = 8w..8w+7 for ALL 4 rows ----
    // W read DIRECT from global: lane l -> row l, chunks 8w..8w+7 = one
    // 128B line at W + l*1024 + w*128. First b128 pulls the line, the
    // remaining 7 are L1 hits. hT broadcast via v_readlane (SGPR src).
    const float* Wg = W + (size_t)l * Hc + 32 * w;
    float acc0 = 0.f, acc1 = 0.f, acc2 = 0.f, acc3 = 0.f;
    const int lbase = 32 * (w & 1);
    #pragma unroll
    for (int qq = 0; qq < 8; ++qq) {
        const float4 wv = *reinterpret_cast<const float4*>(Wg + 4 * qq);
        #pragma unroll
        for (int j = 0; j < 4; ++j) {
            const int   lane = lbase + 4 * qq + j;
            const float wj = (j == 0) ? wv.x : (j == 1) ? wv.y : (j == 2) ? wv.z : wv.w;
            acc0 += wj * rdlane(hh[0], lane);
            acc1 += wj * rdlane(hh[1], lane);
            acc2 += wj * rdlane(hh[2], lane);
            acc3 += wj * rdlane(hh[3], lane);
        }
    }
    part[w][0][l] = acc0;  part[w][1][l] = acc1;
    part[w][2][l] = acc2;  part[w][3][l] = acc3;
    __syncthreads();

    // ---- combine: wave w (<4) owns row w ----
    if (w < 4) {
        float s = bl[l];
        #pragma unroll
        for (int wp = 0; wp < 8; ++wp) s += part[wp][w][l];
        out[(size_t)(blockIdx.x * 4 + w) * Lc + l] = s;
    }
}

extern "C" void kernel_launch(void* const* d_in, const int* in_sizes, int n_in,
                              void* d_out, int out_size, void* d_ws, size_t ws_size,
                              hipStream_t stream) {
    const float* x    = (const float*)d_in[0];
    const float* a_in = (const float*)d_in[1];
    const float* b_in = (const float*)d_in[2];
    const float* a_h  = (const float*)d_in[3];
    const float* b_h  = (const float*)d_in[4];
    const float* W    = (const float*)d_in[5];
    const float* bl   = (const float*)d_in[6];
    float* out = (float*)d_out;

    dim3 grid(Bc / 4), block(512);
    kan_rnn_collapsed<<<grid, block, 0, stream>>>(x, a_in, b_in, a_h, b_h, W, bl, out);
}